// Round 1
// baseline (1771.785 us; speedup 1.0000x reference)
//
#include <hip/hip_runtime.h>
#include <hip/hip_bf16.h>
#include <math.h>

#define DIM 1024
#define D_INNER 2048
#define D_STATE 16
#define D_CONV 4
#define DT_RANK 64
#define B_SZ 2
#define T_LEN 2048
#define NT (B_SZ * T_LEN)  // 4096 tokens

// ---------------------------------------------------------------------------
// Generic tiled fp32 GEMM: C[M,N] = A[M,K] @ B[K,N]  (row-major, strided)
// EPI: 0 = none, 1 = softplus(v + bias[col])
// BM=BN=64, BK=16, 256 threads, 4x4 per-thread micro-tile.
// ---------------------------------------------------------------------------
template <int EPI>
__global__ __launch_bounds__(256) void gemm_f32(
    const float* __restrict__ A, int lda,
    const float* __restrict__ B, int ldb,
    float* __restrict__ C, int ldc,
    int M, int N, int K,
    const float* __restrict__ bias) {
  constexpr int BM = 64, BN = 64, BK = 16, TM = 4, TN = 4;
  __shared__ float As[BK][BM + 1];  // +1 pad: conflict-free transpose store
  __shared__ float Bs[BK][BN];
  const int tid = threadIdx.x;
  const int brow = blockIdx.y * BM;
  const int bcol = blockIdx.x * BN;
  const int tx = tid & 15;   // 16 cols of threads
  const int ty = tid >> 4;   // 16 rows of threads

  float acc[TM][TN];
#pragma unroll
  for (int i = 0; i < TM; i++)
#pragma unroll
    for (int j = 0; j < TN; j++) acc[i][j] = 0.f;

  // A loader: thread -> (row, 4 consecutive k)
  const int a_row = tid >> 2;         // 0..63
  const int a_col = (tid & 3) * 4;    // 0,4,8,12
  // B loader: thread -> (k-row, 4 consecutive cols)
  const int b_row = tid >> 4;         // 0..15
  const int b_col = (tid & 15) * 4;   // 0..60

  const float* Aptr = A + (size_t)(brow + a_row) * lda + a_col;
  const float* Bptr = B + (size_t)b_row * ldb + bcol + b_col;

  for (int k0 = 0; k0 < K; k0 += BK) {
    float4 av = *(const float4*)(Aptr + k0);
    float4 bv = *(const float4*)(Bptr + (size_t)k0 * ldb);
    As[a_col + 0][a_row] = av.x;
    As[a_col + 1][a_row] = av.y;
    As[a_col + 2][a_row] = av.z;
    As[a_col + 3][a_row] = av.w;
    *(float4*)&Bs[b_row][b_col] = bv;
    __syncthreads();
#pragma unroll
    for (int k = 0; k < BK; k++) {
      float a[TM], bb[TN];
#pragma unroll
      for (int i = 0; i < TM; i++) a[i] = As[k][ty * TM + i];
#pragma unroll
      for (int j = 0; j < TN; j++) bb[j] = Bs[k][tx * TN + j];
#pragma unroll
      for (int i = 0; i < TM; i++)
#pragma unroll
        for (int j = 0; j < TN; j++)
          acc[i][j] = fmaf(a[i], bb[j], acc[i][j]);
    }
    __syncthreads();
  }

#pragma unroll
  for (int i = 0; i < TM; i++) {
    const int row = brow + ty * TM + i;
#pragma unroll
    for (int j = 0; j < TN; j++) {
      const int col = bcol + tx * TN + j;
      float v = acc[i][j];
      if (EPI == 1) {
        v += bias[col];
        v = (v > 20.f) ? v : log1pf(expf(v));
      }
      C[(size_t)row * ldc + col] = v;
    }
  }
}

// ---------------------------------------------------------------------------
// Depthwise causal conv(4) + bias + SiLU. Also emits new_conv_state.
// xz layout: [token][4096]; x_in = cols 0..2047.
// ---------------------------------------------------------------------------
__global__ __launch_bounds__(256) void conv_kernel(
    const float* __restrict__ xz,
    const float* __restrict__ conv_state,
    const float* __restrict__ conv_w,
    const float* __restrict__ conv_b,
    float* __restrict__ xconv,
    float* __restrict__ out_conv_state) {
  const int idx = blockIdx.x * 256 + threadIdx.x;  // 0 .. NT*D_INNER-1
  const int d = idx & (D_INNER - 1);
  const int tok = idx >> 11;
  const int t = tok & (T_LEN - 1);
  const int b = tok >> 11;

  const float4 w = *(const float4*)(conv_w + (size_t)d * 4);
  float xs[4];
#pragma unroll
  for (int k = 0; k < 4; k++) {
    const int tp = t + k - 3;
    xs[k] = (tp >= 0)
                ? xz[((size_t)(b * T_LEN + tp)) * 4096 + d]
                : conv_state[((size_t)b * D_INNER + d) * 3 + (tp + 3)];
  }
  float v = xs[0] * w.x + xs[1] * w.y + xs[2] * w.z + xs[3] * w.w + conv_b[d];
  const float sv = v / (1.f + expf(-v));
  xconv[(size_t)tok * D_INNER + d] = sv;
  if (t >= T_LEN - 3) {
    out_conv_state[((size_t)b * D_INNER + d) * 3 + (t - (T_LEN - 3))] = xs[3];
  }
}

// ---------------------------------------------------------------------------
// proj = x_conv @ w_x  -> [token][96] (dt_raw 0..63, B 64..79, C 80..95)
// Block handles 4 tokens; x rows staged in LDS, w_x streamed coalesced.
// ---------------------------------------------------------------------------
__global__ __launch_bounds__(128) void proj_kernel(
    const float* __restrict__ xconv,
    const float* __restrict__ w_x,
    float* __restrict__ proj) {
  __shared__ float xs[4][D_INNER];
  const int tok0 = blockIdx.x * 4;
  const int tid = threadIdx.x;

  const float4* src = (const float4*)(xconv + (size_t)tok0 * D_INNER);
  float4* dst = (float4*)&xs[0][0];
  for (int i = tid; i < 4 * (D_INNER / 4); i += 128) dst[i] = src[i];
  __syncthreads();

  if (tid < 96) {
    float a0 = 0.f, a1 = 0.f, a2 = 0.f, a3 = 0.f;
    for (int k = 0; k < D_INNER; k++) {
      const float w = w_x[(size_t)k * 96 + tid];
      a0 = fmaf(xs[0][k], w, a0);
      a1 = fmaf(xs[1][k], w, a1);
      a2 = fmaf(xs[2][k], w, a2);
      a3 = fmaf(xs[3][k], w, a3);
    }
    proj[(size_t)(tok0 + 0) * 96 + tid] = a0;
    proj[(size_t)(tok0 + 1) * 96 + tid] = a1;
    proj[(size_t)(tok0 + 2) * 96 + tid] = a2;
    proj[(size_t)(tok0 + 3) * 96 + tid] = a3;
  }
}

// ---------------------------------------------------------------------------
// Selective scan. One thread per (b, d, n). 16 state lanes per channel live
// in 16 consecutive lanes; y-reduction via shfl_xor butterfly (width 16).
// Next-step operands prefetched so the h-recurrence fma chain is the only
// serial dependency. Fuses y = (C.h + D*x) * silu(z).
// ---------------------------------------------------------------------------
__global__ __launch_bounds__(256) void scan_kernel(
    const float* __restrict__ dt,
    const float* __restrict__ xconv,
    const float* __restrict__ proj,
    const float* __restrict__ xz,
    const float* __restrict__ A_log,
    const float* __restrict__ D_skip,
    const float* __restrict__ ssm_state,
    float* __restrict__ y,
    float* __restrict__ h_final) {
  const int g = blockIdx.x * 256 + threadIdx.x;  // 0 .. B*D_INNER*16-1
  const int n = g & 15;
  const int bd = g >> 4;            // b*D_INNER + d
  const int d = bd & (D_INNER - 1);
  const int b = bd >> 11;

  const float Acoef = -expf(A_log[(size_t)d * D_STATE + n]);
  float h = ssm_state[(size_t)bd * D_STATE + n];
  const float Dv = D_skip[d];
  const size_t tb = (size_t)b * T_LEN;

  // prefetch t = 0
  float dt_c = dt[(tb + 0) * D_INNER + d];
  float x_c = xconv[(tb + 0) * D_INNER + d];
  float B_c = proj[(tb + 0) * 96 + DT_RANK + n];
  float C_c = proj[(tb + 0) * 96 + DT_RANK + D_STATE + n];
  float z_c = xz[(tb + 0) * 4096 + D_INNER + d];

  for (int t = 0; t < T_LEN; t++) {
    float dt_n = 0.f, x_n = 0.f, B_n = 0.f, C_n = 0.f, z_n = 0.f;
    if (t + 1 < T_LEN) {
      const size_t tt = tb + t + 1;
      dt_n = dt[tt * D_INNER + d];
      x_n = xconv[tt * D_INNER + d];
      B_n = proj[tt * 96 + DT_RANK + n];
      C_n = proj[tt * 96 + DT_RANK + D_STATE + n];
      z_n = xz[tt * 4096 + D_INNER + d];
    }
    const float dA = expf(dt_c * Acoef);
    h = fmaf(dA, h, dt_c * B_c * x_c);
    float yp = h * C_c;
    yp += __shfl_xor(yp, 1, 16);
    yp += __shfl_xor(yp, 2, 16);
    yp += __shfl_xor(yp, 4, 16);
    yp += __shfl_xor(yp, 8, 16);
    if (n == 0) {
      const float yv = yp + Dv * x_c;
      const float sz = z_c / (1.f + expf(-z_c));
      y[(tb + t) * D_INNER + d] = yv * sz;
    }
    dt_c = dt_n; x_c = x_n; B_c = B_n; C_c = C_n; z_c = z_n;
  }
  h_final[(size_t)bd * D_STATE + n] = h;
}

// ---------------------------------------------------------------------------
extern "C" void kernel_launch(void* const* d_in, const int* in_sizes, int n_in,
                              void* d_out, int out_size, void* d_ws,
                              size_t ws_size, hipStream_t stream) {
  const float* x          = (const float*)d_in[0];
  const float* ssm_state  = (const float*)d_in[1];
  const float* conv_state = (const float*)d_in[2];
  const float* w_in       = (const float*)d_in[3];
  const float* conv_w     = (const float*)d_in[4];
  const float* conv_b     = (const float*)d_in[5];
  const float* w_x        = (const float*)d_in[6];
  const float* w_dt       = (const float*)d_in[7];
  const float* b_dt       = (const float*)d_in[8];
  const float* A_log      = (const float*)d_in[9];
  const float* D_skip     = (const float*)d_in[10];
  const float* w_out      = (const float*)d_in[11];

  float* out     = (float*)d_out;                                 // NT*DIM
  float* h_final = out + (size_t)NT * DIM;                        // B*D_INNER*16
  float* ncs     = h_final + (size_t)B_SZ * D_INNER * D_STATE;    // B*D_INNER*3

  float* ws    = (float*)d_ws;
  float* xz    = ws;                          // NT * 4096
  float* xconv = xz + (size_t)NT * 4096;      // NT * 2048
  float* projb = xconv + (size_t)NT * 2048;   // NT * 96
  float* dtb   = projb + (size_t)NT * 96;     // NT * 2048
  float* yb    = dtb + (size_t)NT * 2048;     // NT * 2048

  // 1. xz = x @ w_in : [4096,1024] @ [1024,4096]
  gemm_f32<0><<<dim3((2 * D_INNER) / 64, NT / 64), 256, 0, stream>>>(
      x, DIM, w_in, 2 * D_INNER, xz, 2 * D_INNER, NT, 2 * D_INNER, DIM,
      nullptr);

  // 2. depthwise conv + silu (+ new_conv_state)
  conv_kernel<<<(NT * D_INNER) / 256, 256, 0, stream>>>(
      xz, conv_state, conv_w, conv_b, xconv, ncs);

  // 3. proj = x_conv @ w_x : [4096,2048] @ [2048,96]
  proj_kernel<<<NT / 4, 128, 0, stream>>>(xconv, w_x, projb);

  // 4. dt = softplus(dt_raw @ w_dt + b_dt) : [4096,64] @ [64,2048]
  gemm_f32<1><<<dim3(D_INNER / 64, NT / 64), 256, 0, stream>>>(
      projb, 96, w_dt, D_INNER, dtb, D_INNER, NT, D_INNER, DT_RANK, b_dt);

  // 5. selective scan (+ gate silu(z), + h_final)
  scan_kernel<<<(B_SZ * D_INNER * D_STATE) / 256, 256, 0, stream>>>(
      dtb, xconv, projb, xz, A_log, D_skip, ssm_state, yb, h_final);

  // 6. out = y @ w_out : [4096,2048] @ [2048,1024]
  gemm_f32<0><<<dim3(DIM / 64, NT / 64), 256, 0, stream>>>(
      yb, D_INNER, w_out, DIM, out, DIM, NT, DIM, D_INNER, nullptr);
}

// Round 2
// 1127.799 us; speedup vs baseline: 1.5710x; 1.5710x over previous
//
#include <hip/hip_runtime.h>
#include <hip/hip_bf16.h>
#include <math.h>

#define DIM 1024
#define D_INNER 2048
#define D_STATE 16
#define D_CONV 4
#define DT_RANK 64
#define B_SZ 2
#define T_LEN 2048
#define NT (B_SZ * T_LEN)  // 4096 tokens
#define CH 64              // time chunks for parallel scan
#define CLEN (T_LEN / CH)  // 32 steps per chunk

// ---------------------------------------------------------------------------
// Generic tiled fp32 GEMM: C[M,N] = A[M,K] @ B[K,N]  (row-major, strided)
// EPI: 0 = none, 1 = softplus(v + bias[col])
// ---------------------------------------------------------------------------
template <int EPI>
__global__ __launch_bounds__(256) void gemm_f32(
    const float* __restrict__ A, int lda,
    const float* __restrict__ B, int ldb,
    float* __restrict__ C, int ldc,
    int M, int N, int K,
    const float* __restrict__ bias) {
  constexpr int BM = 64, BN = 64, BK = 16, TM = 4, TN = 4;
  __shared__ float As[BK][BM + 1];
  __shared__ float Bs[BK][BN];
  const int tid = threadIdx.x;
  const int brow = blockIdx.y * BM;
  const int bcol = blockIdx.x * BN;
  const int tx = tid & 15;
  const int ty = tid >> 4;

  float acc[TM][TN];
#pragma unroll
  for (int i = 0; i < TM; i++)
#pragma unroll
    for (int j = 0; j < TN; j++) acc[i][j] = 0.f;

  const int a_row = tid >> 2;
  const int a_col = (tid & 3) * 4;
  const int b_row = tid >> 4;
  const int b_col = (tid & 15) * 4;

  const float* Aptr = A + (size_t)(brow + a_row) * lda + a_col;
  const float* Bptr = B + (size_t)b_row * ldb + bcol + b_col;

  for (int k0 = 0; k0 < K; k0 += BK) {
    float4 av = *(const float4*)(Aptr + k0);
    float4 bv = *(const float4*)(Bptr + (size_t)k0 * ldb);
    As[a_col + 0][a_row] = av.x;
    As[a_col + 1][a_row] = av.y;
    As[a_col + 2][a_row] = av.z;
    As[a_col + 3][a_row] = av.w;
    *(float4*)&Bs[b_row][b_col] = bv;
    __syncthreads();
#pragma unroll
    for (int k = 0; k < BK; k++) {
      float a[TM], bb[TN];
#pragma unroll
      for (int i = 0; i < TM; i++) a[i] = As[k][ty * TM + i];
#pragma unroll
      for (int j = 0; j < TN; j++) bb[j] = Bs[k][tx * TN + j];
#pragma unroll
      for (int i = 0; i < TM; i++)
#pragma unroll
        for (int j = 0; j < TN; j++)
          acc[i][j] = fmaf(a[i], bb[j], acc[i][j]);
    }
    __syncthreads();
  }

#pragma unroll
  for (int i = 0; i < TM; i++) {
    const int row = brow + ty * TM + i;
#pragma unroll
    for (int j = 0; j < TN; j++) {
      const int col = bcol + tx * TN + j;
      float v = acc[i][j];
      if (EPI == 1) {
        v += bias[col];
        v = (v > 20.f) ? v : log1pf(expf(v));
      }
      C[(size_t)row * ldc + col] = v;
    }
  }
}

// ---------------------------------------------------------------------------
// Depthwise causal conv(4) + bias + SiLU. Also emits new_conv_state.
// ---------------------------------------------------------------------------
__global__ __launch_bounds__(256) void conv_kernel(
    const float* __restrict__ xz,
    const float* __restrict__ conv_state,
    const float* __restrict__ conv_w,
    const float* __restrict__ conv_b,
    float* __restrict__ xconv,
    float* __restrict__ out_conv_state) {
  const int idx = blockIdx.x * 256 + threadIdx.x;
  const int d = idx & (D_INNER - 1);
  const int tok = idx >> 11;
  const int t = tok & (T_LEN - 1);
  const int b = tok >> 11;

  const float4 w = *(const float4*)(conv_w + (size_t)d * 4);
  float xs[4];
#pragma unroll
  for (int k = 0; k < 4; k++) {
    const int tp = t + k - 3;
    xs[k] = (tp >= 0)
                ? xz[((size_t)(b * T_LEN + tp)) * 4096 + d]
                : conv_state[((size_t)b * D_INNER + d) * 3 + (tp + 3)];
  }
  float v = xs[0] * w.x + xs[1] * w.y + xs[2] * w.z + xs[3] * w.w + conv_b[d];
  const float sv = v / (1.f + __expf(-v));
  xconv[(size_t)tok * D_INNER + d] = sv;
  if (t >= T_LEN - 3) {
    out_conv_state[((size_t)b * D_INNER + d) * 3 + (t - (T_LEN - 3))] = xs[3];
  }
}

// ---------------------------------------------------------------------------
// proj = x_conv @ w_x  -> [token][96] (dt_raw 0..63, B 64..79, C 80..95)
// ---------------------------------------------------------------------------
__global__ __launch_bounds__(128) void proj_kernel(
    const float* __restrict__ xconv,
    const float* __restrict__ w_x,
    float* __restrict__ proj) {
  __shared__ float xs[4][D_INNER];
  const int tok0 = blockIdx.x * 4;
  const int tid = threadIdx.x;

  const float4* src = (const float4*)(xconv + (size_t)tok0 * D_INNER);
  float4* dst = (float4*)&xs[0][0];
  for (int i = tid; i < 4 * (D_INNER / 4); i += 128) dst[i] = src[i];
  __syncthreads();

  if (tid < 96) {
    float a0 = 0.f, a1 = 0.f, a2 = 0.f, a3 = 0.f;
    for (int k = 0; k < D_INNER; k++) {
      const float w = w_x[(size_t)k * 96 + tid];
      a0 = fmaf(xs[0][k], w, a0);
      a1 = fmaf(xs[1][k], w, a1);
      a2 = fmaf(xs[2][k], w, a2);
      a3 = fmaf(xs[3][k], w, a3);
    }
    proj[(size_t)(tok0 + 0) * 96 + tid] = a0;
    proj[(size_t)(tok0 + 1) * 96 + tid] = a1;
    proj[(size_t)(tok0 + 2) * 96 + tid] = a2;
    proj[(size_t)(tok0 + 3) * 96 + tid] = a3;
  }
}

// ---------------------------------------------------------------------------
// Chunked parallel scan, phase A: per-(b,d,chunk) local scan from h=0.
// Thread layout g = (b*CH + chunk)*D_INNER + d  -> dt/x loads coalesced in d.
// Emits per-chunk (prod dA, h_local) for all 16 states.
// ---------------------------------------------------------------------------
__global__ __launch_bounds__(256) void scan_chunk_kernel(
    const float* __restrict__ dt,
    const float* __restrict__ xconv,
    const float* __restrict__ proj,
    const float* __restrict__ A_log,
    float* __restrict__ hloc,
    float* __restrict__ aprod) {
  const int g = blockIdx.x * 256 + threadIdx.x;
  const int d = g & (D_INNER - 1);
  const int cb = g >> 11;
  const int chunk = cb & (CH - 1);
  const int b = cb >> 6;

  float Ac[D_STATE];
#pragma unroll
  for (int q = 0; q < 4; q++) {
    const float4 al = *(const float4*)(A_log + (size_t)d * D_STATE + q * 4);
    Ac[q * 4 + 0] = -__expf(al.x);
    Ac[q * 4 + 1] = -__expf(al.y);
    Ac[q * 4 + 2] = -__expf(al.z);
    Ac[q * 4 + 3] = -__expf(al.w);
  }
  float h[D_STATE], ap[D_STATE];
#pragma unroll
  for (int n = 0; n < D_STATE; n++) { h[n] = 0.f; ap[n] = 1.f; }

  const size_t tb = (size_t)b * T_LEN + (size_t)chunk * CLEN;
  for (int t = 0; t < CLEN; t++) {
    const size_t row = tb + t;
    const float dtv = dt[row * D_INNER + d];
    const float xv = xconv[row * D_INNER + d];
    const float4* Bq = (const float4*)(proj + row * 96 + DT_RANK);
    float Bv[D_STATE];
#pragma unroll
    for (int q = 0; q < 4; q++) {
      const float4 v = Bq[q];
      Bv[q * 4 + 0] = v.x; Bv[q * 4 + 1] = v.y;
      Bv[q * 4 + 2] = v.z; Bv[q * 4 + 3] = v.w;
    }
    const float dtx = dtv * xv;
#pragma unroll
    for (int n = 0; n < D_STATE; n++) {
      const float dA = __expf(dtv * Ac[n]);
      h[n] = fmaf(dA, h[n], dtx * Bv[n]);
      ap[n] *= dA;
    }
  }
  float4* hout = (float4*)(hloc + (size_t)g * D_STATE);
  float4* aout = (float4*)(aprod + (size_t)g * D_STATE);
#pragma unroll
  for (int q = 0; q < 4; q++) {
    hout[q] = make_float4(h[q * 4 + 0], h[q * 4 + 1], h[q * 4 + 2], h[q * 4 + 3]);
    aout[q] = make_float4(ap[q * 4 + 0], ap[q * 4 + 1], ap[q * 4 + 2], ap[q * 4 + 3]);
  }
}

// ---------------------------------------------------------------------------
// Phase B: sequential combine over the 64 chunks per (b,d,n).
// Writes chunk-entry state h_in in place into hloc; emits h_final.
// ---------------------------------------------------------------------------
__global__ __launch_bounds__(256) void scan_combine_kernel(
    const float* __restrict__ ssm_state,
    float* __restrict__ hloc,       // in: h_local; out: h_in (chunk entry)
    const float* __restrict__ aprod,
    float* __restrict__ h_final) {
  const int j = blockIdx.x * 256 + threadIdx.x;  // (b*D_INNER+d)*16+n
  const int b = j >> 15;
  const int r = j & 32767;
  float h = ssm_state[j];
  for (int c = 0; c < CH; c++) {
    const size_t idx = ((size_t)(b * CH + c) << 15) + r;
    const float hl = hloc[idx];
    const float a = aprod[idx];
    hloc[idx] = h;               // chunk-entry state for phase C
    h = fmaf(a, h, hl);
  }
  h_final[j] = h;
}

// ---------------------------------------------------------------------------
// Phase C: re-scan each chunk from its entry state; in-register C.h dot,
// fused D-skip + silu(z) gate -> y.
// ---------------------------------------------------------------------------
__global__ __launch_bounds__(256) void scan_emit_kernel(
    const float* __restrict__ dt,
    const float* __restrict__ xconv,
    const float* __restrict__ proj,
    const float* __restrict__ xz,
    const float* __restrict__ A_log,
    const float* __restrict__ D_skip,
    const float* __restrict__ hin,
    float* __restrict__ y) {
  const int g = blockIdx.x * 256 + threadIdx.x;
  const int d = g & (D_INNER - 1);
  const int cb = g >> 11;
  const int chunk = cb & (CH - 1);
  const int b = cb >> 6;

  float Ac[D_STATE];
#pragma unroll
  for (int q = 0; q < 4; q++) {
    const float4 al = *(const float4*)(A_log + (size_t)d * D_STATE + q * 4);
    Ac[q * 4 + 0] = -__expf(al.x);
    Ac[q * 4 + 1] = -__expf(al.y);
    Ac[q * 4 + 2] = -__expf(al.z);
    Ac[q * 4 + 3] = -__expf(al.w);
  }
  float h[D_STATE];
  const float4* hi = (const float4*)(hin + (size_t)g * D_STATE);
#pragma unroll
  for (int q = 0; q < 4; q++) {
    const float4 v = hi[q];
    h[q * 4 + 0] = v.x; h[q * 4 + 1] = v.y;
    h[q * 4 + 2] = v.z; h[q * 4 + 3] = v.w;
  }
  const float Dv = D_skip[d];

  const size_t tb = (size_t)b * T_LEN + (size_t)chunk * CLEN;
  for (int t = 0; t < CLEN; t++) {
    const size_t row = tb + t;
    const float dtv = dt[row * D_INNER + d];
    const float xv = xconv[row * D_INNER + d];
    const float zv = xz[row * 4096 + D_INNER + d];
    const float4* Bq = (const float4*)(proj + row * 96 + DT_RANK);
    const float4* Cq = (const float4*)(proj + row * 96 + DT_RANK + D_STATE);
    float Bv[D_STATE], Cv[D_STATE];
#pragma unroll
    for (int q = 0; q < 4; q++) {
      const float4 bv = Bq[q];
      Bv[q * 4 + 0] = bv.x; Bv[q * 4 + 1] = bv.y;
      Bv[q * 4 + 2] = bv.z; Bv[q * 4 + 3] = bv.w;
      const float4 cv = Cq[q];
      Cv[q * 4 + 0] = cv.x; Cv[q * 4 + 1] = cv.y;
      Cv[q * 4 + 2] = cv.z; Cv[q * 4 + 3] = cv.w;
    }
    const float dtx = dtv * xv;
    float acc = 0.f;
#pragma unroll
    for (int n = 0; n < D_STATE; n++) {
      const float dA = __expf(dtv * Ac[n]);
      h[n] = fmaf(dA, h[n], dtx * Bv[n]);
      acc = fmaf(h[n], Cv[n], acc);
    }
    const float yv = fmaf(Dv, xv, acc);
    const float sz = zv / (1.f + __expf(-zv));
    y[row * D_INNER + d] = yv * sz;
  }
}

// ---------------------------------------------------------------------------
extern "C" void kernel_launch(void* const* d_in, const int* in_sizes, int n_in,
                              void* d_out, int out_size, void* d_ws,
                              size_t ws_size, hipStream_t stream) {
  const float* x          = (const float*)d_in[0];
  const float* ssm_state  = (const float*)d_in[1];
  const float* conv_state = (const float*)d_in[2];
  const float* w_in       = (const float*)d_in[3];
  const float* conv_w     = (const float*)d_in[4];
  const float* conv_b     = (const float*)d_in[5];
  const float* w_x        = (const float*)d_in[6];
  const float* w_dt       = (const float*)d_in[7];
  const float* b_dt       = (const float*)d_in[8];
  const float* A_log      = (const float*)d_in[9];
  const float* D_skip     = (const float*)d_in[10];
  const float* w_out      = (const float*)d_in[11];

  float* out     = (float*)d_out;                               // NT*DIM
  float* h_final = out + (size_t)NT * DIM;                      // B*D_INNER*16
  float* ncs     = h_final + (size_t)B_SZ * D_INNER * D_STATE;  // B*D_INNER*3

  float* ws    = (float*)d_ws;
  float* xz    = ws;                          // NT * 4096
  float* xconv = xz + (size_t)NT * 4096;      // NT * 2048
  float* projb = xconv + (size_t)NT * 2048;   // NT * 96
  float* dtb   = projb + (size_t)NT * 96;     // NT * 2048
  float* yb    = dtb + (size_t)NT * 2048;     // NT * 2048
  // hloc/aprod alias yb (dead before phase C writes y); hin is separate.
  float* hloc  = yb;                                        // B*CH*D_INNER*16
  float* aprod = yb + (size_t)B_SZ * CH * D_INNER * D_STATE;
  float* hin   = yb + (size_t)NT * 2048;                    // B*CH*D_INNER*16

  // 1. xz = x @ w_in : [4096,1024] @ [1024,4096]
  gemm_f32<0><<<dim3((2 * D_INNER) / 64, NT / 64), 256, 0, stream>>>(
      x, DIM, w_in, 2 * D_INNER, xz, 2 * D_INNER, NT, 2 * D_INNER, DIM,
      nullptr);

  // 2. depthwise conv + silu (+ new_conv_state)
  conv_kernel<<<(NT * D_INNER) / 256, 256, 0, stream>>>(
      xz, conv_state, conv_w, conv_b, xconv, ncs);

  // 3. proj = x_conv @ w_x : [4096,2048] @ [2048,96]
  proj_kernel<<<NT / 4, 128, 0, stream>>>(xconv, w_x, projb);

  // 4. dt = softplus(dt_raw @ w_dt + b_dt) : [4096,64] @ [64,2048]
  gemm_f32<1><<<dim3(D_INNER / 64, NT / 64), 256, 0, stream>>>(
      projb, 96, w_dt, D_INNER, dtb, D_INNER, NT, D_INNER, DT_RANK, b_dt);

  // 5. chunk-parallel selective scan
  scan_chunk_kernel<<<(B_SZ * CH * D_INNER) / 256, 256, 0, stream>>>(
      dtb, xconv, projb, A_log, hloc, aprod);
  scan_combine_kernel<<<(B_SZ * D_INNER * D_STATE) / 256, 256, 0, stream>>>(
      ssm_state, hloc, aprod, h_final);
  scan_emit_kernel<<<(B_SZ * CH * D_INNER) / 256, 256, 0, stream>>>(
      dtb, xconv, projb, xz, A_log, D_skip, hloc, yb);

  // 6. out = y @ w_out : [4096,2048] @ [2048,1024]
  gemm_f32<0><<<dim3(DIM / 64, NT / 64), 256, 0, stream>>>(
      yb, D_INNER, w_out, DIM, out, DIM, NT, DIM, D_INNER, nullptr);
}

// Round 3
// 391.763 us; speedup vs baseline: 4.5226x; 2.8788x over previous
//
#include <hip/hip_runtime.h>
#include <hip/hip_bf16.h>
#include <math.h>

#define DIM 1024
#define D_INNER 2048
#define D_STATE 16
#define D_CONV 4
#define DT_RANK 64
#define B_SZ 2
#define T_LEN 2048
#define NT (B_SZ * T_LEN)  // 4096 tokens
#define CH 64              // time chunks for parallel scan
#define CLEN (T_LEN / CH)  // 32 steps per chunk
#define PSPLIT 8           // split-K for proj GEMM

typedef __attribute__((ext_vector_type(8))) short short8;
typedef __attribute__((ext_vector_type(4))) float floatx4;

#define GLOAD_LDS16(gp, lp)                                      \
  __builtin_amdgcn_global_load_lds(                              \
      (const __attribute__((address_space(1))) void*)(gp),       \
      (__attribute__((address_space(3))) void*)(lp), 16, 0, 0)

// ---------------------------------------------------------------------------
// bf16 MFMA GEMM: C[M,N] = A[M,K] @ Bt[N,K]^T, fp32 accumulate.
// 128x128 tile, BK=32, 4 waves (2x2 of 64x64), global_load_lds staging,
// XOR-swizzled LDS k-slots so ds_read_b128 frag reads are conflict-free.
// EPI: 0 = fp32 store, 1 = softplus(v+bias[col]) fp32 store, 2 = bf16 store.
// Split-K via blockIdx.z: k-window [z*kLen, (z+1)*kLen), output slice z.
// ---------------------------------------------------------------------------
template <int EPI>
__global__ __launch_bounds__(256) void gemm_bf16(
    const __hip_bfloat16* __restrict__ A, int lda,
    const __hip_bfloat16* __restrict__ Bt, int ldb,
    float* __restrict__ C, __hip_bfloat16* __restrict__ Cb, int ldc,
    const float* __restrict__ bias, int kLen) {
  __shared__ short As[128 * 32];
  __shared__ short Bs[128 * 32];
  const int tid = threadIdx.x;
  const int w = tid >> 6;
  const int lane = tid & 63;
  const int tileM = blockIdx.y * 128;
  const int tileN = blockIdx.x * 128;
  const int k0 = blockIdx.z * kLen;
  C += (size_t)blockIdx.z * gridDim.y * 128 * ldc;

  const int srow = lane >> 2;   // staging: row within 16-row group
  const int sslot = lane & 3;   // staging: 16B slot within 64B row

  floatx4 acc[4][4] = {};

  const int wm = w & 1, wn = w >> 1;
  const int ml = lane & 15;
  const int kq = lane >> 4;
  const int swz = (ml >> 2) & 3;  // frag-read k-slot swizzle

  for (int kk = 0; kk < kLen; kk += 32) {
#pragma unroll
    for (int i = 0; i < 2; i++) {
      const int r = w * 32 + i * 16 + srow;
      const int kg = sslot ^ ((r >> 2) & 3);
      const size_t kcol = (size_t)(k0 + kk + kg * 8);
      GLOAD_LDS16(A + (size_t)(tileM + r) * lda + kcol,
                  As + (size_t)(w * 32 + i * 16) * 32);
      GLOAD_LDS16(Bt + (size_t)(tileN + r) * ldb + kcol,
                  Bs + (size_t)(w * 32 + i * 16) * 32);
    }
    __syncthreads();

    short8 aF[4], bF[4];
#pragma unroll
    for (int t = 0; t < 4; t++) {
      const int sa = (kq ^ swz) * 8;
      aF[t] = *(const short8*)(As + (wm * 64 + t * 16 + ml) * 32 + sa);
      bF[t] = *(const short8*)(Bs + (wn * 64 + t * 16 + ml) * 32 + sa);
    }
#pragma unroll
    for (int i = 0; i < 4; i++)
#pragma unroll
      for (int j = 0; j < 4; j++)
        acc[i][j] =
            __builtin_amdgcn_mfma_f32_16x16x32_bf16(aF[i], bF[j], acc[i][j], 0, 0, 0);
    __syncthreads();
  }

  // C/D layout: col = lane&15, row = (lane>>4)*4 + reg   [m89-verified]
#pragma unroll
  for (int i = 0; i < 4; i++) {
    const int row0 = tileM + wm * 64 + i * 16 + kq * 4;
#pragma unroll
    for (int j = 0; j < 4; j++) {
      const int col = tileN + wn * 64 + j * 16 + ml;
#pragma unroll
      for (int r = 0; r < 4; r++) {
        float v = acc[i][j][r];
        const size_t off = (size_t)(row0 + r) * ldc + col;
        if (EPI == 1) {
          v += bias[col];
          v = (v > 20.f) ? v : log1pf(__expf(v));
          C[off] = v;
        } else if (EPI == 2) {
          Cb[off] = __float2bfloat16(v);
        } else {
          C[off] = v;
        }
      }
    }
  }
}

// ---------------------------------------------------------------------------
// fp32 -> bf16 elementwise cast (n multiple of 4)
// ---------------------------------------------------------------------------
__global__ __launch_bounds__(256) void cast_bf16_kernel(
    const float* __restrict__ src, __hip_bfloat16* __restrict__ dst, int n4) {
  const int i = blockIdx.x * 256 + threadIdx.x;
  if (i < n4) {
    const float4 v = ((const float4*)src)[i];
    alignas(8) __hip_bfloat16 h[4] = {
        __float2bfloat16(v.x), __float2bfloat16(v.y),
        __float2bfloat16(v.z), __float2bfloat16(v.w)};
    ((short4*)dst)[i] = *(const short4*)h;
  }
}

// ---------------------------------------------------------------------------
// Transpose + cast: src[R][C] fp32 -> dst[Cpad][R] bf16 (zero-fill pad rows).
// Grid: (Cpad/32, R/32), 256 threads.
// ---------------------------------------------------------------------------
__global__ __launch_bounds__(256) void transpose_cast_kernel(
    const float* __restrict__ src, int R, int C,
    __hip_bfloat16* __restrict__ dst, int Cpad) {
  __shared__ float t[32][33];
  const int c0 = blockIdx.x * 32;
  const int r0 = blockIdx.y * 32;
  const int lx = threadIdx.x & 31, ly = threadIdx.x >> 5;
  for (int i = ly; i < 32; i += 8) {
    const int c = c0 + lx;
    t[i][lx] = (c < C) ? src[(size_t)(r0 + i) * C + c] : 0.f;
  }
  __syncthreads();
  for (int i = ly; i < 32; i += 8) {
    const int dr = c0 + i;
    if (dr < Cpad) dst[(size_t)dr * R + r0 + lx] = __float2bfloat16(t[lx][i]);
  }
}

// ---------------------------------------------------------------------------
// Depthwise causal conv(4) + bias + SiLU; emits fp32 + bf16 xconv and
// new_conv_state. xz is bf16 [token][4096] (x half = cols 0..2047).
// ---------------------------------------------------------------------------
__global__ __launch_bounds__(256) void conv_kernel(
    const __hip_bfloat16* __restrict__ xz,
    const float* __restrict__ conv_state,
    const float* __restrict__ conv_w,
    const float* __restrict__ conv_b,
    float* __restrict__ xconv,
    __hip_bfloat16* __restrict__ xconv_bf,
    float* __restrict__ out_conv_state) {
  const int idx = blockIdx.x * 256 + threadIdx.x;
  const int d = idx & (D_INNER - 1);
  const int tok = idx >> 11;
  const int t = tok & (T_LEN - 1);
  const int b = tok >> 11;

  const float4 w = *(const float4*)(conv_w + (size_t)d * 4);
  float xs[4];
#pragma unroll
  for (int k = 0; k < 4; k++) {
    const int tp = t + k - 3;
    xs[k] = (tp >= 0)
                ? __bfloat162float(xz[((size_t)(b * T_LEN + tp)) * 4096 + d])
                : conv_state[((size_t)b * D_INNER + d) * 3 + (tp + 3)];
  }
  float v = xs[0] * w.x + xs[1] * w.y + xs[2] * w.z + xs[3] * w.w + conv_b[d];
  const float sv = v / (1.f + __expf(-v));
  xconv[(size_t)tok * D_INNER + d] = sv;
  xconv_bf[(size_t)tok * D_INNER + d] = __float2bfloat16(sv);
  if (t >= T_LEN - 3) {
    out_conv_state[((size_t)b * D_INNER + d) * 3 + (t - (T_LEN - 3))] = xs[3];
  }
}

// ---------------------------------------------------------------------------
// Reduce proj split-K partials [PSPLIT][NT][128] -> projBC fp32 [NT][32]
// (B at 0..15, C at 16..31) + dt_raw bf16 [NT][64].
// ---------------------------------------------------------------------------
__global__ __launch_bounds__(256) void proj_reduce_kernel(
    const float* __restrict__ Ppart,
    float* __restrict__ projBC,
    __hip_bfloat16* __restrict__ dtraw) {
  const int idx = blockIdx.x * 256 + threadIdx.x;  // row*128+col
  const int col = idx & 127, row = idx >> 7;
  if (col >= 96) return;
  float s = 0.f;
#pragma unroll
  for (int p = 0; p < PSPLIT; p++) s += Ppart[(size_t)p * NT * 128 + idx];
  if (col < 64) dtraw[(size_t)row * 64 + col] = __float2bfloat16(s);
  else projBC[(size_t)row * 32 + (col - 64)] = s;
}

// ---------------------------------------------------------------------------
// Chunked parallel scan, phase A: per-(b,d,chunk) local scan from h=0.
// ---------------------------------------------------------------------------
__global__ __launch_bounds__(256) void scan_chunk_kernel(
    const float* __restrict__ dt,
    const float* __restrict__ xconv,
    const float* __restrict__ projBC,
    const float* __restrict__ A_log,
    float* __restrict__ hloc,
    float* __restrict__ aprod) {
  const int g = blockIdx.x * 256 + threadIdx.x;
  const int d = g & (D_INNER - 1);
  const int cb = g >> 11;
  const int chunk = cb & (CH - 1);
  const int b = cb >> 6;

  float Ac[D_STATE];
#pragma unroll
  for (int q = 0; q < 4; q++) {
    const float4 al = *(const float4*)(A_log + (size_t)d * D_STATE + q * 4);
    Ac[q * 4 + 0] = -__expf(al.x);
    Ac[q * 4 + 1] = -__expf(al.y);
    Ac[q * 4 + 2] = -__expf(al.z);
    Ac[q * 4 + 3] = -__expf(al.w);
  }
  float h[D_STATE], ap[D_STATE];
#pragma unroll
  for (int n = 0; n < D_STATE; n++) { h[n] = 0.f; ap[n] = 1.f; }

  const size_t tb = (size_t)b * T_LEN + (size_t)chunk * CLEN;
  for (int t = 0; t < CLEN; t++) {
    const size_t row = tb + t;
    const float dtv = dt[row * D_INNER + d];
    const float xv = xconv[row * D_INNER + d];
    const float4* Bq = (const float4*)(projBC + row * 32);
    float Bv[D_STATE];
#pragma unroll
    for (int q = 0; q < 4; q++) {
      const float4 v = Bq[q];
      Bv[q * 4 + 0] = v.x; Bv[q * 4 + 1] = v.y;
      Bv[q * 4 + 2] = v.z; Bv[q * 4 + 3] = v.w;
    }
    const float dtx = dtv * xv;
#pragma unroll
    for (int n = 0; n < D_STATE; n++) {
      const float dA = __expf(dtv * Ac[n]);
      h[n] = fmaf(dA, h[n], dtx * Bv[n]);
      ap[n] *= dA;
    }
  }
  float4* hout = (float4*)(hloc + (size_t)g * D_STATE);
  float4* aout = (float4*)(aprod + (size_t)g * D_STATE);
#pragma unroll
  for (int q = 0; q < 4; q++) {
    hout[q] = make_float4(h[q * 4 + 0], h[q * 4 + 1], h[q * 4 + 2], h[q * 4 + 3]);
    aout[q] = make_float4(ap[q * 4 + 0], ap[q * 4 + 1], ap[q * 4 + 2], ap[q * 4 + 3]);
  }
}

// ---------------------------------------------------------------------------
// Phase B: sequential combine over chunks; hloc becomes chunk-entry states.
// ---------------------------------------------------------------------------
__global__ __launch_bounds__(256) void scan_combine_kernel(
    const float* __restrict__ ssm_state,
    float* __restrict__ hloc,
    const float* __restrict__ aprod,
    float* __restrict__ h_final) {
  const int j = blockIdx.x * 256 + threadIdx.x;
  const int b = j >> 15;
  const int r = j & 32767;
  float h = ssm_state[j];
  for (int c = 0; c < CH; c++) {
    const size_t idx = ((size_t)(b * CH + c) << 15) + r;
    const float hl = hloc[idx];
    const float a = aprod[idx];
    hloc[idx] = h;
    h = fmaf(a, h, hl);
  }
  h_final[j] = h;
}

// ---------------------------------------------------------------------------
// Phase C: re-scan from entry state; C.h dot + D-skip + silu(z) gate -> y bf16.
// ---------------------------------------------------------------------------
__global__ __launch_bounds__(256) void scan_emit_kernel(
    const float* __restrict__ dt,
    const float* __restrict__ xconv,
    const float* __restrict__ projBC,
    const __hip_bfloat16* __restrict__ xz,
    const float* __restrict__ A_log,
    const float* __restrict__ D_skip,
    const float* __restrict__ hin,
    __hip_bfloat16* __restrict__ y) {
  const int g = blockIdx.x * 256 + threadIdx.x;
  const int d = g & (D_INNER - 1);
  const int cb = g >> 11;
  const int chunk = cb & (CH - 1);
  const int b = cb >> 6;

  float Ac[D_STATE];
#pragma unroll
  for (int q = 0; q < 4; q++) {
    const float4 al = *(const float4*)(A_log + (size_t)d * D_STATE + q * 4);
    Ac[q * 4 + 0] = -__expf(al.x);
    Ac[q * 4 + 1] = -__expf(al.y);
    Ac[q * 4 + 2] = -__expf(al.z);
    Ac[q * 4 + 3] = -__expf(al.w);
  }
  float h[D_STATE];
  const float4* hi = (const float4*)(hin + (size_t)g * D_STATE);
#pragma unroll
  for (int q = 0; q < 4; q++) {
    const float4 v = hi[q];
    h[q * 4 + 0] = v.x; h[q * 4 + 1] = v.y;
    h[q * 4 + 2] = v.z; h[q * 4 + 3] = v.w;
  }
  const float Dv = D_skip[d];

  const size_t tb = (size_t)b * T_LEN + (size_t)chunk * CLEN;
  for (int t = 0; t < CLEN; t++) {
    const size_t row = tb + t;
    const float dtv = dt[row * D_INNER + d];
    const float xv = xconv[row * D_INNER + d];
    const float zv = __bfloat162float(xz[row * 4096 + D_INNER + d]);
    const float4* Bq = (const float4*)(projBC + row * 32);
    const float4* Cq = (const float4*)(projBC + row * 32 + 16);
    float Bv[D_STATE], Cv[D_STATE];
#pragma unroll
    for (int q = 0; q < 4; q++) {
      const float4 bv = Bq[q];
      Bv[q * 4 + 0] = bv.x; Bv[q * 4 + 1] = bv.y;
      Bv[q * 4 + 2] = bv.z; Bv[q * 4 + 3] = bv.w;
      const float4 cv = Cq[q];
      Cv[q * 4 + 0] = cv.x; Cv[q * 4 + 1] = cv.y;
      Cv[q * 4 + 2] = cv.z; Cv[q * 4 + 3] = cv.w;
    }
    const float dtx = dtv * xv;
    float acc = 0.f;
#pragma unroll
    for (int n = 0; n < D_STATE; n++) {
      const float dA = __expf(dtv * Ac[n]);
      h[n] = fmaf(dA, h[n], dtx * Bv[n]);
      acc = fmaf(h[n], Cv[n], acc);
    }
    const float yv = fmaf(Dv, xv, acc);
    const float sz = zv / (1.f + __expf(-zv));
    y[row * D_INNER + d] = __float2bfloat16(yv * sz);
  }
}

// ---------------------------------------------------------------------------
extern "C" void kernel_launch(void* const* d_in, const int* in_sizes, int n_in,
                              void* d_out, int out_size, void* d_ws,
                              size_t ws_size, hipStream_t stream) {
  const float* x          = (const float*)d_in[0];
  const float* ssm_state  = (const float*)d_in[1];
  const float* conv_state = (const float*)d_in[2];
  const float* w_in       = (const float*)d_in[3];
  const float* conv_w     = (const float*)d_in[4];
  const float* conv_b     = (const float*)d_in[5];
  const float* w_x        = (const float*)d_in[6];
  const float* w_dt       = (const float*)d_in[7];
  const float* b_dt       = (const float*)d_in[8];
  const float* A_log      = (const float*)d_in[9];
  const float* D_skip     = (const float*)d_in[10];
  const float* w_out      = (const float*)d_in[11];

  float* out     = (float*)d_out;
  float* h_final = out + (size_t)NT * DIM;
  float* ncs     = h_final + (size_t)B_SZ * D_INNER * D_STATE;

  // Workspace layout (lifetimes disjoint within regions):
  char* p = (char*)d_ws;
  __hip_bfloat16* xz_bf = (__hip_bfloat16*)p;            p += (size_t)NT * 4096 * 2;
  float* xconv          = (float*)p;                     p += (size_t)NT * 2048 * 4;
  float* dtb            = (float*)p;                     p += (size_t)NT * 2048 * 4;
  char* regionA         = p;                             p += (size_t)PSPLIT * NT * 128 * 4;  // 16.8MB
  char* regionB         = p;                             p += (size_t)B_SZ * CH * D_INNER * D_STATE * 4;  // 16.8MB
  char* regionC         = p;                             p += (size_t)NT * 2048 * 2;  // 16.8MB
  float* projBC         = (float*)p;                     p += (size_t)NT * 32 * 4;
  __hip_bfloat16* dtraw = (__hip_bfloat16*)p;            p += (size_t)NT * 64 * 2;
  __hip_bfloat16* wx_t  = (__hip_bfloat16*)p;            p += (size_t)128 * 2048 * 2;
  __hip_bfloat16* wdt_t = (__hip_bfloat16*)p;            p += (size_t)2048 * 64 * 2;
  __hip_bfloat16* wout_t= (__hip_bfloat16*)p;            p += (size_t)1024 * 2048 * 2;

  __hip_bfloat16* x_bf   = (__hip_bfloat16*)regionA;  // dead after GEMM1
  float*          Ppart  = (float*)regionA;           // proj partials (steps 4-5)
  float*          hloc   = (float*)regionA;           // scan (steps 7-9)
  __hip_bfloat16* win_t  = (__hip_bfloat16*)regionB;  // dead after GEMM1
  float*          aprod  = (float*)regionB;           // scan
  __hip_bfloat16* xconv_bf = (__hip_bfloat16*)regionC;  // dead after proj GEMM
  __hip_bfloat16* y_bf     = (__hip_bfloat16*)regionC;  // written in phase C

  // 0. casts / transposes to bf16
  cast_bf16_kernel<<<(NT * DIM / 4 + 255) / 256, 256, 0, stream>>>(
      x, x_bf, NT * DIM / 4);
  transpose_cast_kernel<<<dim3(4096 / 32, 1024 / 32), 256, 0, stream>>>(
      w_in, 1024, 4096, win_t, 4096);
  transpose_cast_kernel<<<dim3(128 / 32, 2048 / 32), 256, 0, stream>>>(
      w_x, 2048, 96, wx_t, 128);
  transpose_cast_kernel<<<dim3(2048 / 32, 64 / 32), 256, 0, stream>>>(
      w_dt, 64, 2048, wdt_t, 2048);
  transpose_cast_kernel<<<dim3(1024 / 32, 2048 / 32), 256, 0, stream>>>(
      w_out, 2048, 1024, wout_t, 1024);

  // 1. xz = x @ w_in  (bf16 out): M=4096, N=4096, K=1024
  gemm_bf16<2><<<dim3(32, 32, 1), 256, 0, stream>>>(
      x_bf, DIM, win_t, DIM, nullptr, xz_bf, 4096, nullptr, DIM);

  // 2. depthwise conv + silu (+ new_conv_state)
  conv_kernel<<<(NT * D_INNER) / 256, 256, 0, stream>>>(
      xz_bf, conv_state, conv_w, conv_b, xconv, xconv_bf, ncs);

  // 3. proj = x_conv @ w_x (padded N=128, split-K=8)
  gemm_bf16<0><<<dim3(1, 32, PSPLIT), 256, 0, stream>>>(
      xconv_bf, D_INNER, wx_t, D_INNER, Ppart, nullptr, 128, nullptr,
      D_INNER / PSPLIT);
  proj_reduce_kernel<<<(NT * 128) / 256, 256, 0, stream>>>(
      Ppart, projBC, dtraw);

  // 4. dt = softplus(dt_raw @ w_dt + b_dt): M=4096, N=2048, K=64
  gemm_bf16<1><<<dim3(16, 32, 1), 256, 0, stream>>>(
      dtraw, DT_RANK, wdt_t, DT_RANK, dtb, nullptr, D_INNER, b_dt, DT_RANK);

  // 5. chunk-parallel selective scan
  scan_chunk_kernel<<<(B_SZ * CH * D_INNER) / 256, 256, 0, stream>>>(
      dtb, xconv, projBC, A_log, hloc, aprod);
  scan_combine_kernel<<<(B_SZ * D_INNER * D_STATE) / 256, 256, 0, stream>>>(
      ssm_state, hloc, aprod, h_final);
  scan_emit_kernel<<<(B_SZ * CH * D_INNER) / 256, 256, 0, stream>>>(
      dtb, xconv, projBC, xz_bf, A_log, D_skip, hloc, y_bf);

  // 6. out = y @ w_out: M=4096, N=1024, K=2048
  gemm_bf16<0><<<dim3(8, 32, 1), 256, 0, stream>>>(
      y_bf, D_INNER, wout_t, D_INNER, out, nullptr, DIM, nullptr, D_INNER);
}

// Round 4
// 363.236 us; speedup vs baseline: 4.8778x; 1.0785x over previous
//
#include <hip/hip_runtime.h>
#include <hip/hip_bf16.h>
#include <math.h>

#define DIM 1024
#define D_INNER 2048
#define D_STATE 16
#define D_CONV 4
#define DT_RANK 64
#define B_SZ 2
#define T_LEN 2048
#define NT (B_SZ * T_LEN)  // 4096 tokens
#define CH 64              // time chunks for parallel scan
#define CLEN (T_LEN / CH)  // 32 steps per chunk
#define PSPLIT 8           // split-K for proj GEMM

typedef __attribute__((ext_vector_type(8))) short short8;
typedef __attribute__((ext_vector_type(4))) float floatx4;

#define GLOAD_LDS16(gp, lp)                                      \
  __builtin_amdgcn_global_load_lds(                              \
      (const __attribute__((address_space(1))) void*)(gp),       \
      (__attribute__((address_space(3))) void*)(lp), 16, 0, 0)

// ---------------------------------------------------------------------------
// bf16 MFMA GEMM: C[M,N] = A[M,K] @ Bt[N,K]^T, fp32 accumulate.
// BM=128, BN=JT*32 (JT=4 -> 128, JT=2 -> 64), BK=32, 4 waves (2x2).
// Bank-conflict-free swizzle: chunk(r,s) stored at slot s^((r>>1)&3); within
// any 8 consecutive frag-read lanes the chunk%8 values are then distinct.
// EPI: 0 = fp32 store, 1 = softplus(v+bias[col]) fp32 store, 2 = bf16 store.
// Split-K via blockIdx.z: k-window [z*kLen, (z+1)*kLen), output slice z.
// ---------------------------------------------------------------------------
template <int EPI, int JT>
__global__ __launch_bounds__(256) void gemm_bf16(
    const __hip_bfloat16* __restrict__ A, int lda,
    const __hip_bfloat16* __restrict__ Bt, int ldb,
    float* __restrict__ C, __hip_bfloat16* __restrict__ Cb, int ldc,
    const float* __restrict__ bias, int kLen) {
  __shared__ short As[128 * 32];
  __shared__ short Bs[JT * 32 * 32];
  const int tid = threadIdx.x;
  const int w = tid >> 6;
  const int lane = tid & 63;
  const int tileM = blockIdx.y * 128;
  const int tileN = blockIdx.x * (JT * 32);
  const int k0 = blockIdx.z * kLen;
  C += (size_t)blockIdx.z * gridDim.y * 128 * ldc;

  const int srow = lane >> 2;   // staging: row within 16-row group
  const int sslot = lane & 3;   // staging: 16B slot within 64B row

  floatx4 acc[4][JT] = {};

  const int wm = w & 1, wn = w >> 1;
  const int ml = lane & 15;
  const int kq = lane >> 4;
  const int swz = (ml >> 1) & 3;  // conflict-free k-slot swizzle

  for (int kk = 0; kk < kLen; kk += 32) {
#pragma unroll
    for (int i = 0; i < 2; i++) {  // A: 128 rows
      const int r = w * 32 + i * 16 + srow;
      const int kg = sslot ^ ((r >> 1) & 3);
      GLOAD_LDS16(A + (size_t)(tileM + r) * lda + (k0 + kk + kg * 8),
                  As + (size_t)(w * 32 + i * 16) * 32);
    }
#pragma unroll
    for (int i = 0; i < JT / 2; i++) {  // B: JT*32 rows
      const int r = w * (JT * 8) + i * 16 + srow;
      const int kg = sslot ^ ((r >> 1) & 3);
      GLOAD_LDS16(Bt + (size_t)(tileN + r) * ldb + (k0 + kk + kg * 8),
                  Bs + (size_t)(w * (JT * 8) + i * 16) * 32);
    }
    __syncthreads();

    short8 aF[4], bF[JT];
    const int sa = (kq ^ swz) * 8;
#pragma unroll
    for (int t = 0; t < 4; t++)
      aF[t] = *(const short8*)(As + (wm * 64 + t * 16 + ml) * 32 + sa);
#pragma unroll
    for (int j = 0; j < JT; j++)
      bF[j] = *(const short8*)(Bs + (wn * (JT * 16) + j * 16 + ml) * 32 + sa);
#pragma unroll
    for (int i = 0; i < 4; i++)
#pragma unroll
      for (int j = 0; j < JT; j++)
        acc[i][j] =
            __builtin_amdgcn_mfma_f32_16x16x32_bf16(aF[i], bF[j], acc[i][j], 0, 0, 0);
    __syncthreads();
  }

  // C/D layout: col = lane&15, row = (lane>>4)*4 + reg
#pragma unroll
  for (int i = 0; i < 4; i++) {
    const int row0 = tileM + wm * 64 + i * 16 + kq * 4;
#pragma unroll
    for (int j = 0; j < JT; j++) {
      const int col = tileN + wn * (JT * 16) + j * 16 + ml;
#pragma unroll
      for (int r = 0; r < 4; r++) {
        float v = acc[i][j][r];
        const size_t off = (size_t)(row0 + r) * ldc + col;
        if (EPI == 1) {
          v += bias[col];
          v = (v > 20.f) ? v : log1pf(__expf(v));
          C[off] = v;
        } else if (EPI == 2) {
          Cb[off] = __float2bfloat16(v);
        } else {
          C[off] = v;
        }
      }
    }
  }
}

// ---------------------------------------------------------------------------
// Fused prep: cast x -> bf16; transpose+cast the 4 weights (zero-fill pads).
// ---------------------------------------------------------------------------
__device__ __forceinline__ void tp_tile(const float* __restrict__ src, int R,
                                        int C, __hip_bfloat16* __restrict__ dst,
                                        int Cpad, int bx, int by,
                                        float (*t)[33]) {
  const int c0 = bx * 32;
  const int r0 = by * 32;
  const int lx = threadIdx.x & 31, ly = threadIdx.x >> 5;
  for (int i = ly; i < 32; i += 8) {
    const int c = c0 + lx;
    t[i][lx] = (c < C) ? src[(size_t)(r0 + i) * C + c] : 0.f;
  }
  __syncthreads();
  for (int i = ly; i < 32; i += 8) {
    const int dr = c0 + i;
    if (dr < Cpad) dst[(size_t)dr * R + r0 + lx] = __float2bfloat16(t[lx][i]);
  }
}

__global__ __launch_bounds__(256) void prep_kernel(
    const float* __restrict__ x, const float* __restrict__ w_in,
    const float* __restrict__ w_x, const float* __restrict__ w_dt,
    const float* __restrict__ w_out, __hip_bfloat16* __restrict__ x_bf,
    __hip_bfloat16* __restrict__ win_t, __hip_bfloat16* __restrict__ wx_t,
    __hip_bfloat16* __restrict__ wdt_t, __hip_bfloat16* __restrict__ wout_t) {
  __shared__ float t[32][33];
  int id = blockIdx.x;
  if (id < 4096) {  // cast x: NT*DIM/4 = 1048576 float4's
    const int i = id * 256 + threadIdx.x;
    const float4 v = ((const float4*)x)[i];
    alignas(8) __hip_bfloat16 h[4] = {
        __float2bfloat16(v.x), __float2bfloat16(v.y),
        __float2bfloat16(v.z), __float2bfloat16(v.w)};
    ((short4*)x_bf)[i] = *(const short4*)h;
    return;
  }
  id -= 4096;
  if (id < 4096) { tp_tile(w_in, 1024, 4096, win_t, 4096, id & 127, id >> 7, t); return; }
  id -= 4096;
  if (id < 256) { tp_tile(w_x, 2048, 96, wx_t, 128, id & 3, id >> 2, t); return; }
  id -= 256;
  if (id < 128) { tp_tile(w_dt, 64, 2048, wdt_t, 2048, id & 63, id >> 6, t); return; }
  id -= 128;
  tp_tile(w_out, 2048, 1024, wout_t, 1024, id & 31, id >> 5, t);
}

// ---------------------------------------------------------------------------
// Depthwise causal conv(4) + bias + SiLU; fp32 + bf16 xconv, new_conv_state.
// ---------------------------------------------------------------------------
__global__ __launch_bounds__(256) void conv_kernel(
    const __hip_bfloat16* __restrict__ xz,
    const float* __restrict__ conv_state,
    const float* __restrict__ conv_w,
    const float* __restrict__ conv_b,
    float* __restrict__ xconv,
    __hip_bfloat16* __restrict__ xconv_bf,
    float* __restrict__ out_conv_state) {
  const int idx = blockIdx.x * 256 + threadIdx.x;
  const int d = idx & (D_INNER - 1);
  const int tok = idx >> 11;
  const int t = tok & (T_LEN - 1);
  const int b = tok >> 11;

  const float4 w = *(const float4*)(conv_w + (size_t)d * 4);
  float xs[4];
#pragma unroll
  for (int k = 0; k < 4; k++) {
    const int tp = t + k - 3;
    xs[k] = (tp >= 0)
                ? __bfloat162float(xz[((size_t)(b * T_LEN + tp)) * 4096 + d])
                : conv_state[((size_t)b * D_INNER + d) * 3 + (tp + 3)];
  }
  float v = xs[0] * w.x + xs[1] * w.y + xs[2] * w.z + xs[3] * w.w + conv_b[d];
  const float sv = v / (1.f + __expf(-v));
  xconv[(size_t)tok * D_INNER + d] = sv;
  xconv_bf[(size_t)tok * D_INNER + d] = __float2bfloat16(sv);
  if (t >= T_LEN - 3) {
    out_conv_state[((size_t)b * D_INNER + d) * 3 + (t - (T_LEN - 3))] = xs[3];
  }
}

// ---------------------------------------------------------------------------
// Reduce proj split-K partials [PSPLIT][NT][128] -> projBC fp32 [NT][32]
// (B at 0..15, C at 16..31) + dt_raw bf16 [NT][64].
// ---------------------------------------------------------------------------
__global__ __launch_bounds__(256) void proj_reduce_kernel(
    const float* __restrict__ Ppart,
    float* __restrict__ projBC,
    __hip_bfloat16* __restrict__ dtraw) {
  const int idx = blockIdx.x * 256 + threadIdx.x;  // row*128+col
  const int col = idx & 127, row = idx >> 7;
  if (col >= 96) return;
  float s = 0.f;
#pragma unroll
  for (int p = 0; p < PSPLIT; p++) s += Ppart[(size_t)p * NT * 128 + idx];
  if (col < 64) dtraw[(size_t)row * 64 + col] = __float2bfloat16(s);
  else projBC[(size_t)row * 32 + (col - 64)] = s;
}

// ---------------------------------------------------------------------------
// Phase A: per-(b,d,chunk) local scan from h=0. Emits h_local and sum(dt)
// (prod dA over the chunk == exp(Ac*sum(dt)), recomputed in phase B).
// ---------------------------------------------------------------------------
__global__ __launch_bounds__(256) void scan_chunk_kernel(
    const float* __restrict__ dt,
    const float* __restrict__ xconv,
    const float* __restrict__ projBC,
    const float* __restrict__ A_log,
    float* __restrict__ hloc,
    float* __restrict__ sdt) {
  const int g = blockIdx.x * 256 + threadIdx.x;
  const int d = g & (D_INNER - 1);
  const int cb = g >> 11;
  const int chunk = cb & (CH - 1);
  const int b = cb >> 6;

  float Ac[D_STATE];
#pragma unroll
  for (int q = 0; q < 4; q++) {
    const float4 al = *(const float4*)(A_log + (size_t)d * D_STATE + q * 4);
    Ac[q * 4 + 0] = -__expf(al.x);
    Ac[q * 4 + 1] = -__expf(al.y);
    Ac[q * 4 + 2] = -__expf(al.z);
    Ac[q * 4 + 3] = -__expf(al.w);
  }
  float h[D_STATE];
#pragma unroll
  for (int n = 0; n < D_STATE; n++) h[n] = 0.f;
  float dtsum = 0.f;

  const size_t tb = (size_t)b * T_LEN + (size_t)chunk * CLEN;
  for (int t = 0; t < CLEN; t++) {
    const size_t row = tb + t;
    const float dtv = dt[row * D_INNER + d];
    const float xv = xconv[row * D_INNER + d];
    const float4* Bq = (const float4*)(projBC + row * 32);
    float Bv[D_STATE];
#pragma unroll
    for (int q = 0; q < 4; q++) {
      const float4 v = Bq[q];
      Bv[q * 4 + 0] = v.x; Bv[q * 4 + 1] = v.y;
      Bv[q * 4 + 2] = v.z; Bv[q * 4 + 3] = v.w;
    }
    const float dtx = dtv * xv;
    dtsum += dtv;
#pragma unroll
    for (int n = 0; n < D_STATE; n++) {
      const float dA = __expf(dtv * Ac[n]);
      h[n] = fmaf(dA, h[n], dtx * Bv[n]);
    }
  }
  float4* hout = (float4*)(hloc + (size_t)g * D_STATE);
#pragma unroll
  for (int q = 0; q < 4; q++)
    hout[q] = make_float4(h[q * 4 + 0], h[q * 4 + 1], h[q * 4 + 2], h[q * 4 + 3]);
  sdt[g] = dtsum;
}

// ---------------------------------------------------------------------------
// Phase B: sequential combine over chunks; hloc becomes chunk-entry states.
// ap(chunk) = exp(Ac * sum_dt(chunk)).
// ---------------------------------------------------------------------------
__global__ __launch_bounds__(256) void scan_combine_kernel(
    const float* __restrict__ ssm_state,
    float* __restrict__ hloc,
    const float* __restrict__ sdt,
    const float* __restrict__ A_log,
    float* __restrict__ h_final) {
  const int j = blockIdx.x * 256 + threadIdx.x;
  const int b = j >> 15;
  const int r = j & 32767;       // d*16+n
  const int d = r >> 4;
  const float Acoef = -__expf(A_log[r]);
  float h = ssm_state[j];
  for (int c = 0; c < CH; c++) {
    const size_t idx = ((size_t)(b * CH + c) << 15) + r;
    const float hl = hloc[idx];
    const float a = __expf(Acoef * sdt[(size_t)(b * CH + c) * D_INNER + d]);
    hloc[idx] = h;
    h = fmaf(a, h, hl);
  }
  h_final[j] = h;
}

// ---------------------------------------------------------------------------
// Phase C: re-scan from entry state; C.h dot + D-skip + silu(z) gate -> y bf16.
// ---------------------------------------------------------------------------
__global__ __launch_bounds__(256) void scan_emit_kernel(
    const float* __restrict__ dt,
    const float* __restrict__ xconv,
    const float* __restrict__ projBC,
    const __hip_bfloat16* __restrict__ xz,
    const float* __restrict__ A_log,
    const float* __restrict__ D_skip,
    const float* __restrict__ hin,
    __hip_bfloat16* __restrict__ y) {
  const int g = blockIdx.x * 256 + threadIdx.x;
  const int d = g & (D_INNER - 1);
  const int cb = g >> 11;
  const int chunk = cb & (CH - 1);
  const int b = cb >> 6;

  float Ac[D_STATE];
#pragma unroll
  for (int q = 0; q < 4; q++) {
    const float4 al = *(const float4*)(A_log + (size_t)d * D_STATE + q * 4);
    Ac[q * 4 + 0] = -__expf(al.x);
    Ac[q * 4 + 1] = -__expf(al.y);
    Ac[q * 4 + 2] = -__expf(al.z);
    Ac[q * 4 + 3] = -__expf(al.w);
  }
  float h[D_STATE];
  const float4* hi = (const float4*)(hin + (size_t)g * D_STATE);
#pragma unroll
  for (int q = 0; q < 4; q++) {
    const float4 v = hi[q];
    h[q * 4 + 0] = v.x; h[q * 4 + 1] = v.y;
    h[q * 4 + 2] = v.z; h[q * 4 + 3] = v.w;
  }
  const float Dv = D_skip[d];

  const size_t tb = (size_t)b * T_LEN + (size_t)chunk * CLEN;
  for (int t = 0; t < CLEN; t++) {
    const size_t row = tb + t;
    const float dtv = dt[row * D_INNER + d];
    const float xv = xconv[row * D_INNER + d];
    const float zv = __bfloat162float(xz[row * 4096 + D_INNER + d]);
    const float4* Bq = (const float4*)(projBC + row * 32);
    const float4* Cq = (const float4*)(projBC + row * 32 + 16);
    float Bv[D_STATE], Cv[D_STATE];
#pragma unroll
    for (int q = 0; q < 4; q++) {
      const float4 bv = Bq[q];
      Bv[q * 4 + 0] = bv.x; Bv[q * 4 + 1] = bv.y;
      Bv[q * 4 + 2] = bv.z; Bv[q * 4 + 3] = bv.w;
      const float4 cv = Cq[q];
      Cv[q * 4 + 0] = cv.x; Cv[q * 4 + 1] = cv.y;
      Cv[q * 4 + 2] = cv.z; Cv[q * 4 + 3] = cv.w;
    }
    const float dtx = dtv * xv;
    float acc = 0.f;
#pragma unroll
    for (int n = 0; n < D_STATE; n++) {
      const float dA = __expf(dtv * Ac[n]);
      h[n] = fmaf(dA, h[n], dtx * Bv[n]);
      acc = fmaf(h[n], Cv[n], acc);
    }
    const float yv = fmaf(Dv, xv, acc);
    const float sz = zv / (1.f + __expf(-zv));
    y[row * D_INNER + d] = __float2bfloat16(yv * sz);
  }
}

// ---------------------------------------------------------------------------
extern "C" void kernel_launch(void* const* d_in, const int* in_sizes, int n_in,
                              void* d_out, int out_size, void* d_ws,
                              size_t ws_size, hipStream_t stream) {
  const float* x          = (const float*)d_in[0];
  const float* ssm_state  = (const float*)d_in[1];
  const float* conv_state = (const float*)d_in[2];
  const float* w_in       = (const float*)d_in[3];
  const float* conv_w     = (const float*)d_in[4];
  const float* conv_b     = (const float*)d_in[5];
  const float* w_x        = (const float*)d_in[6];
  const float* w_dt       = (const float*)d_in[7];
  const float* b_dt       = (const float*)d_in[8];
  const float* A_log      = (const float*)d_in[9];
  const float* D_skip     = (const float*)d_in[10];
  const float* w_out      = (const float*)d_in[11];

  float* out     = (float*)d_out;
  float* h_final = out + (size_t)NT * DIM;
  float* ncs     = h_final + (size_t)B_SZ * D_INNER * D_STATE;

  // Workspace layout:
  char* p = (char*)d_ws;
  __hip_bfloat16* xz_bf = (__hip_bfloat16*)p;            p += (size_t)NT * 4096 * 2;
  float* xconv          = (float*)p;                     p += (size_t)NT * 2048 * 4;
  float* dtb            = (float*)p;                     p += (size_t)NT * 2048 * 4;
  char* regionA         = p;                             p += (size_t)PSPLIT * NT * 128 * 4;  // 16.8MB
  char* regionB         = p;                             p += (size_t)B_SZ * CH * D_INNER * D_STATE * 4;  // 16.8MB
  char* regionC         = p;                             p += (size_t)NT * 2048 * 2;  // 16.8MB
  float* projBC         = (float*)p;                     p += (size_t)NT * 32 * 4;
  __hip_bfloat16* dtraw = (__hip_bfloat16*)p;            p += (size_t)NT * 64 * 2;
  __hip_bfloat16* wx_t  = (__hip_bfloat16*)p;            p += (size_t)128 * 2048 * 2;
  __hip_bfloat16* wdt_t = (__hip_bfloat16*)p;            p += (size_t)2048 * 64 * 2;
  __hip_bfloat16* wout_t= (__hip_bfloat16*)p;            p += (size_t)1024 * 2048 * 2;

  __hip_bfloat16* x_bf   = (__hip_bfloat16*)regionA;    // dead after GEMM1
  float*          Ppart  = (float*)regionA;             // proj partials
  float*          hloc   = (float*)regionA;             // scan phases
  __hip_bfloat16* win_t  = (__hip_bfloat16*)regionB;    // dead after GEMM1
  float*          sdt    = (float*)regionB;             // scan (1MB)
  __hip_bfloat16* xconv_bf = (__hip_bfloat16*)regionC;  // dead after proj GEMM
  __hip_bfloat16* y_bf     = (__hip_bfloat16*)regionC;  // phase C output

  // 0. fused prep: cast x, transpose+cast 4 weights
  prep_kernel<<<4096 + 4096 + 256 + 128 + 2048, 256, 0, stream>>>(
      x, w_in, w_x, w_dt, w_out, x_bf, win_t, wx_t, wdt_t, wout_t);

  // 1. xz = x @ w_in (bf16 out): M=4096, N=4096, K=1024
  gemm_bf16<2, 4><<<dim3(32, 32, 1), 256, 0, stream>>>(
      x_bf, DIM, win_t, DIM, nullptr, xz_bf, 4096, nullptr, DIM);

  // 2. depthwise conv + silu (+ new_conv_state)
  conv_kernel<<<(NT * D_INNER) / 256, 256, 0, stream>>>(
      xz_bf, conv_state, conv_w, conv_b, xconv, xconv_bf, ncs);

  // 3. proj = x_conv @ w_x (padded N=128, split-K=8)
  gemm_bf16<0, 4><<<dim3(1, 32, PSPLIT), 256, 0, stream>>>(
      xconv_bf, D_INNER, wx_t, D_INNER, Ppart, nullptr, 128, nullptr,
      D_INNER / PSPLIT);
  proj_reduce_kernel<<<(NT * 128) / 256, 256, 0, stream>>>(
      Ppart, projBC, dtraw);

  // 4. dt = softplus(dt_raw @ w_dt + b_dt): M=4096, N=2048, K=64
  gemm_bf16<1, 4><<<dim3(16, 32, 1), 256, 0, stream>>>(
      dtraw, DT_RANK, wdt_t, DT_RANK, dtb, nullptr, D_INNER, b_dt, DT_RANK);

  // 5. chunk-parallel selective scan
  scan_chunk_kernel<<<(B_SZ * CH * D_INNER) / 256, 256, 0, stream>>>(
      dtb, xconv, projBC, A_log, hloc, sdt);
  scan_combine_kernel<<<(B_SZ * D_INNER * D_STATE) / 256, 256, 0, stream>>>(
      ssm_state, hloc, sdt, A_log, h_final);
  scan_emit_kernel<<<(B_SZ * CH * D_INNER) / 256, 256, 0, stream>>>(
      dtb, xconv, projBC, xz_bf, A_log, D_skip, hloc, y_bf);

  // 6. out = y @ w_out (BN=64 -> 512 blocks): M=4096, N=1024, K=2048
  gemm_bf16<0, 2><<<dim3(16, 32, 1), 256, 0, stream>>>(
      y_bf, D_INNER, wout_t, D_INNER, out, nullptr, DIM, nullptr, D_INNER);
}